// Round 1
// baseline (640.637 us; speedup 1.0000x reference)
//
#include <hip/hip_runtime.h>
#include <math.h>

#define NB 4
#define HH 180
#define WWW 180
#define SPATIAL (HH*WWW)     // 32400
#define CH_HID 170

typedef short v8s __attribute__((ext_vector_type(8)));
typedef float v4f __attribute__((ext_vector_type(4)));

// order-preserving float<->uint map for atomic min/max
__device__ __forceinline__ unsigned fmap(float f) {
    unsigned u = __float_as_uint(f);
    return (u & 0x80000000u) ? ~u : (u | 0x80000000u);
}
__device__ __forceinline__ float funmap(unsigned u) {
    unsigned b = (u & 0x80000000u) ? (u & 0x7FFFFFFFu) : ~u;
    return __uint_as_float(b);
}
// fp32 -> bf16 bits, round-to-nearest-even
__device__ __forceinline__ unsigned short f2bf(float f) {
    unsigned u = __float_as_uint(f);
    u += 0x7FFFu + ((u >> 16) & 1);
    return (unsigned short)(u >> 16);
}

// ---- init stats: min slots = +max-mapped, max slots = 0 ----
__global__ void k_init(unsigned* stats) {
    int i = blockIdx.x * 256 + threadIdx.x;
    if (i < NB * 512) {
        int j = i & 511;
        bool is_min = (j < 128) || (j >= 256 && j < 384);
        stats[i] = is_min ? 0xFFFFFFFFu : 0u;
    }
}

// ---- transpose Wf1/Wf2 [k][n] fp32 -> WT [n][k] bf16 ----
__global__ void k_prep(const float* __restrict__ Wf1, const float* __restrict__ Wf2,
                       unsigned short* __restrict__ W1T, unsigned short* __restrict__ W2T) {
    const float* W = blockIdx.y ? Wf2 : Wf1;
    unsigned short* WT = blockIdx.y ? W2T : W1T;
    __shared__ float t[32][33];
    int bx = blockIdx.x & 7, by = blockIdx.x >> 3;
    int lx = threadIdx.x & 31, ly = threadIdx.x >> 5;
    for (int i = 0; i < 4; ++i)
        t[ly + i*8][lx] = W[(by*32 + ly + i*8)*256 + bx*32 + lx];
    __syncthreads();
    for (int i = 0; i < 4; ++i)
        WT[(bx*32 + ly + i*8)*256 + by*32 + lx] = f2bf(t[lx][ly + i*8]);
}

// ---- segment min/max over lidar + gathered cam, batch_idx sorted ----
__global__ void k_reduce(const float* __restrict__ lidar, const float* __restrict__ img,
                         const int* __restrict__ bidx, const int* __restrict__ yidx,
                         const int* __restrict__ xidx,
                         unsigned* __restrict__ stats, int N, int chunk) {
    int tid = threadIdx.x;
    int c = tid & 127;
    int cam = tid >> 7;
    int vbeg = blockIdx.x * chunk;
    int vend = min(vbeg + chunk, N);
    float mn = INFINITY, mx = -INFINITY;
    int cur_b = -1;
    for (int v = vbeg; v < vend; ++v) {
        int b = bidx[v];
        if (b != cur_b) {
            if (cur_b >= 0) {
                int base = cur_b*512 + cam*256 + c;
                atomicMin(&stats[base], fmap(mn));
                atomicMax(&stats[base + 128], fmap(mx));
            }
            cur_b = b; mn = INFINITY; mx = -INFINITY;
        }
        float val;
        if (cam == 0) {
            val = lidar[v*128 + c];
        } else {
            int row = b*SPATIAL + yidx[v]*WWW + xidx[v];
            row = min(row, SPATIAL - 2);       // faithful reference clamp (b>=1 -> 32398)
            val = img[c*SPATIAL + row];        // row < SPATIAL after clamp => img_bev[0]
        }
        mn = fminf(mn, val); mx = fmaxf(mx, val);
    }
    if (cur_b >= 0) {
        int base = cur_b*512 + cam*256 + c;
        atomicMin(&stats[base], fmap(mn));
        atomicMax(&stats[base + 128], fmap(mx));
    }
}

// ---- tiny attention MLPs: block = (batch, net) ----
__global__ void k_mlp(const unsigned* __restrict__ stats,
                      const float* __restrict__ Wl1, const float* __restrict__ Wl2,
                      const float* __restrict__ Wc1, const float* __restrict__ Wc2,
                      float* __restrict__ att) {
    __shared__ float cat[512];
    __shared__ float hid[CH_HID];
    int b = blockIdx.x >> 1;
    int net = blockIdx.x & 1;
    const float* W1 = net ? Wc1 : Wl1;
    const float* W2 = net ? Wc2 : Wl2;
    int tid = threadIdx.x;
    for (int j = tid; j < 512; j += 256) cat[j] = funmap(stats[b*512 + j]);
    __syncthreads();
    if (tid < CH_HID) {
        float s = 0.f;
        for (int k = 0; k < 512; ++k) s += cat[k] * W1[k*CH_HID + tid];
        hid[tid] = fmaxf(s, 0.f);
    }
    __syncthreads();
    if (tid < 128) {
        float s = 0.f;
        for (int k = 0; k < CH_HID; ++k) s += hid[k] * W2[k*128 + tid];
        s = fmaxf(s, 0.f);
        att[b*256 + net*128 + tid] = 1.f / (1.f + expf(-s));
    }
}

// ---- main fused kernel: gate -> [64,256]bf16 tile -> MFMA MLP -> out ----
__global__ __launch_bounds__(256, 2)
void k_main(const float* __restrict__ lidar, const float* __restrict__ img,
            const int* __restrict__ bidx, const int* __restrict__ yidx,
            const int* __restrict__ xidx, const float* __restrict__ att,
            const unsigned short* __restrict__ W1T, const unsigned short* __restrict__ W2T,
            float* __restrict__ out, int N) {
    // sA row stride 264 (=16B-aligned, +8 pad breaks bank aliasing); sB stride 72
    __shared__ __align__(16) unsigned short sA[64][264];
    __shared__ __align__(16) unsigned short sB[256][72];
    const int tid = threadIdx.x;
    const int v0 = blockIdx.x * 64;

    { // prologue: fused[m][c] = gated features, bf16, into sA
        const int c = tid;
        const int cam = c >> 7;
        const int ch = c & 127;
        for (int m = 0; m < 64; ++m) {
            int v = v0 + m;
            float val = 0.f;
            if (v < N) {
                int b = bidx[v];
                float a = att[b*256 + c];
                if (cam == 0) {
                    val = lidar[v*128 + ch] * a;
                } else {
                    int row = b*SPATIAL + yidx[v]*WWW + xidx[v];
                    row = min(row, SPATIAL - 2);
                    val = img[ch*SPATIAL + row] * a;
                }
            }
            sA[m][c] = f2bf(val);
        }
    }

    const int wave = tid >> 6;
    const int lane = tid & 63;
    const int ml = lane & 15;       // A: m row / B: n col
    const int q = lane >> 4;        // quad: k = q*8 + j

    for (int layer = 0; layer < 2; ++layer) {
        const unsigned short* WT = layer ? W2T : W1T;
        v4f acc[4][4];
        const v4f zz = {0.f, 0.f, 0.f, 0.f};
        for (int rt = 0; rt < 4; ++rt)
            for (int ct = 0; ct < 4; ++ct) acc[rt][ct] = zz;

        for (int k0 = 0; k0 < 256; k0 += 64) {
            __syncthreads();   // previous chunk / prologue / h-writes all done
            // stage WT[n][k0..k0+64) -> sB (coalesced 16B loads)
            for (int i = 0; i < 8; ++i) {
                int id = i*256 + tid;
                int n = id >> 3;
                int seg = (id & 7) * 8;
                *(v8s*)&sB[n][seg] = *(const v8s*)&WT[n*256 + k0 + seg];
            }
            __syncthreads();
            for (int ks = 0; ks < 2; ++ks) {           // two 32-K MFMA steps per chunk
                v8s a[4];
                const int ka = k0 + ks*32 + q*8;
                for (int rt = 0; rt < 4; ++rt)
                    a[rt] = *(const v8s*)&sA[rt*16 + ml][ka];
                const int kb = ks*32 + q*8;
                for (int ct = 0; ct < 4; ++ct) {
                    v8s bf = *(const v8s*)&sB[wave*64 + ct*16 + ml][kb];
                    for (int rt = 0; rt < 4; ++rt)
                        acc[rt][ct] = __builtin_amdgcn_mfma_f32_16x16x32_bf16(
                            a[rt], bf, acc[rt][ct], 0, 0, 0);
                }
            }
        }
        __syncthreads();   // all sA reads done before overwrite / final stores
        if (layer == 0) {
            // C/D layout: col = lane&15, row = q*4 + reg
            for (int rt = 0; rt < 4; ++rt)
                for (int ct = 0; ct < 4; ++ct)
                    for (int r = 0; r < 4; ++r)
                        sA[rt*16 + q*4 + r][wave*64 + ct*16 + ml] =
                            f2bf(fmaxf(acc[rt][ct][r], 0.f));
        } else {
            for (int rt = 0; rt < 4; ++rt)
                for (int ct = 0; ct < 4; ++ct) {
                    const int col = wave*64 + ct*16 + ml;
                    for (int r = 0; r < 4; ++r) {
                        int v = v0 + rt*16 + q*4 + r;
                        if (v < N) out[v*256 + col] = fmaxf(acc[rt][ct][r], 0.f);
                    }
                }
        }
    }
}

extern "C" void kernel_launch(void* const* d_in, const int* in_sizes, int n_in,
                              void* d_out, int out_size, void* d_ws, size_t ws_size,
                              hipStream_t stream) {
    const float* lidar = (const float*)d_in[0];
    const float* img   = (const float*)d_in[1];
    const int*   bidx  = (const int*)d_in[2];
    const int*   yidx  = (const int*)d_in[3];
    const int*   xidx  = (const int*)d_in[4];
    const float* Wl1   = (const float*)d_in[5];
    const float* Wl2   = (const float*)d_in[6];
    const float* Wc1   = (const float*)d_in[7];
    const float* Wc2   = (const float*)d_in[8];
    const float* Wf1   = (const float*)d_in[9];
    const float* Wf2   = (const float*)d_in[10];
    float* out = (float*)d_out;
    const int N = in_sizes[0] / 128;

    // workspace layout: [stats 8KB][att 4KB][pad][W1T 128KB][W2T 128KB]
    unsigned* stats = (unsigned*)d_ws;
    float* att = (float*)((char*)d_ws + 8192);
    unsigned short* W1T = (unsigned short*)((char*)d_ws + 16384);
    unsigned short* W2T = (unsigned short*)((char*)d_ws + 16384 + 131072);

    k_init<<<8, 256, 0, stream>>>(stats);
    k_prep<<<dim3(64, 2), 256, 0, stream>>>(Wf1, Wf2, W1T, W2T);
    const int rblocks = 640;
    const int chunk = (N + rblocks - 1) / rblocks;
    k_reduce<<<rblocks, 256, 0, stream>>>(lidar, img, bidx, yidx, xidx, stats, N, chunk);
    k_mlp<<<8, 256, 0, stream>>>(stats, Wl1, Wl2, Wc1, Wc2, att);
    k_main<<<(N + 63) / 64, 256, 0, stream>>>(lidar, img, bidx, yidx, xidx, att, W1T, W2T, out, N);
}

// Round 2
// 493.757 us; speedup vs baseline: 1.2975x; 1.2975x over previous
//
#include <hip/hip_runtime.h>
#include <math.h>

#define NB 4
#define HH 180
#define WWW 180
#define SPATIAL (HH*WWW)     // 32400
#define CH_HID 170

typedef short v8s __attribute__((ext_vector_type(8)));
typedef short v4s __attribute__((ext_vector_type(4)));
typedef float v4f __attribute__((ext_vector_type(4)));

// order-preserving float<->uint map for atomic min/max
__device__ __forceinline__ unsigned fmap(float f) {
    unsigned u = __float_as_uint(f);
    return (u & 0x80000000u) ? ~u : (u | 0x80000000u);
}
__device__ __forceinline__ float funmap(unsigned u) {
    unsigned b = (u & 0x80000000u) ? (u & 0x7FFFFFFFu) : ~u;
    return __uint_as_float(b);
}
// fp32 -> bf16 bits, round-to-nearest-even
__device__ __forceinline__ unsigned short f2bf(float f) {
    unsigned u = __float_as_uint(f);
    u += 0x7FFFu + ((u >> 16) & 1);
    return (unsigned short)(u >> 16);
}

// ---- init stats: min slots = +max-mapped, max slots = 0 ----
__global__ void k_init(unsigned* stats) {
    int i = blockIdx.x * 256 + threadIdx.x;
    if (i < NB * 512) {
        int j = i & 511;
        bool is_min = (j < 128) || (j >= 256 && j < 384);
        stats[i] = is_min ? 0xFFFFFFFFu : 0u;
    }
}

// ---- transpose Wf1/Wf2 [k][n] fp32 -> WT [n][k] bf16 ----
__global__ void k_prep(const float* __restrict__ Wf1, const float* __restrict__ Wf2,
                       unsigned short* __restrict__ W1T, unsigned short* __restrict__ W2T) {
    const float* W = blockIdx.y ? Wf2 : Wf1;
    unsigned short* WT = blockIdx.y ? W2T : W1T;
    __shared__ float t[32][33];
    int bx = blockIdx.x & 7, by = blockIdx.x >> 3;
    int lx = threadIdx.x & 31, ly = threadIdx.x >> 5;
    for (int i = 0; i < 4; ++i)
        t[ly + i*8][lx] = W[(by*32 + ly + i*8)*256 + bx*32 + lx];
    __syncthreads();
    for (int i = 0; i < 4; ++i)
        WT[(bx*32 + ly + i*8)*256 + by*32 + lx] = f2bf(t[lx][ly + i*8]);
}

// ---- transpose img batch 0 [128][32400] -> camT [32400][128] fp32 ----
// (reference clamp bug => only batch-0 rows are ever gathered)
__global__ void k_timg(const float* __restrict__ img, float* __restrict__ camT) {
    __shared__ float tile[32][33];
    int s0 = blockIdx.x * 32, c0 = blockIdx.y * 32;
    int lx = threadIdx.x & 31, ly = threadIdx.x >> 5;   // ly in 0..7
    for (int i = 0; i < 4; ++i) {
        int s = s0 + lx;
        if (s < SPATIAL)
            tile[ly + i*8][lx] = img[(c0 + ly + i*8) * SPATIAL + s];
    }
    __syncthreads();
    for (int i = 0; i < 4; ++i) {
        int s = s0 + ly + i*8;
        if (s < SPATIAL)
            camT[s*128 + c0 + lx] = tile[lx][ly + i*8];
    }
}

// ---- segment min/max over lidar + gathered camT, batch_idx sorted ----
// block handles `chunk` voxels (<=256); 4 voxels per iteration, float4/thread
__global__ void k_reduce(const float* __restrict__ lidar, const float* __restrict__ camT,
                         const int* __restrict__ bidx, const int* __restrict__ yidx,
                         const int* __restrict__ xidx,
                         unsigned* __restrict__ stats, int N, int chunk) {
    __shared__ int sb[256];
    __shared__ int srow[256];
    const int tid = threadIdx.x;
    const int vbeg = blockIdx.x * chunk;
    const int cnt = min(chunk, N - vbeg);
    if (cnt <= 0) return;
    if (tid < cnt) {
        int v = vbeg + tid;
        int b = bidx[v];
        int row = b*SPATIAL + yidx[v]*WWW + xidx[v];
        sb[tid] = b;
        srow[tid] = min(row, SPATIAL - 2);
    }
    __syncthreads();

    const int sub = tid >> 6;            // voxel sub-slot 0..3 (uniform per wave)
    const int c4 = (tid & 63) * 4;       // channel group (0..252)
    const bool cam = (c4 >= 128);
    const int min_off = cam ? (c4 + 128) : c4;   // +128 more for max

    float mn[4] = {INFINITY, INFINITY, INFINITY, INFINITY};
    float mx[4] = {-INFINITY, -INFINITY, -INFINITY, -INFINITY};
    int cur_b = -1;
    for (int idx = sub; idx < cnt; idx += 4) {
        int b = sb[idx];
        if (b != cur_b) {
            if (cur_b >= 0) {
                int base = cur_b*512 + min_off;
                for (int j = 0; j < 4; ++j) {
                    atomicMin(&stats[base + j], fmap(mn[j]));
                    atomicMax(&stats[base + 128 + j], fmap(mx[j]));
                    mn[j] = INFINITY; mx[j] = -INFINITY;
                }
            }
            cur_b = b;
        }
        const float* src = cam ? &camT[srow[idx]*128 + (c4 - 128)]
                               : &lidar[(size_t)(vbeg + idx)*128 + c4];
        v4f val = *(const v4f*)src;
        for (int j = 0; j < 4; ++j) {
            mn[j] = fminf(mn[j], val[j]);
            mx[j] = fmaxf(mx[j], val[j]);
        }
    }
    if (cur_b >= 0) {
        int base = cur_b*512 + min_off;
        for (int j = 0; j < 4; ++j) {
            atomicMin(&stats[base + j], fmap(mn[j]));
            atomicMax(&stats[base + 128 + j], fmap(mx[j]));
        }
    }
}

// ---- tiny attention MLPs: block = (batch, net) ----
__global__ void k_mlp(const unsigned* __restrict__ stats,
                      const float* __restrict__ Wl1, const float* __restrict__ Wl2,
                      const float* __restrict__ Wc1, const float* __restrict__ Wc2,
                      float* __restrict__ att) {
    __shared__ float cat[512];
    __shared__ float hid[CH_HID];
    int b = blockIdx.x >> 1;
    int net = blockIdx.x & 1;
    const float* W1 = net ? Wc1 : Wl1;
    const float* W2 = net ? Wc2 : Wl2;
    int tid = threadIdx.x;
    for (int j = tid; j < 512; j += 256) cat[j] = funmap(stats[b*512 + j]);
    __syncthreads();
    if (tid < CH_HID) {
        float s = 0.f;
        for (int k = 0; k < 512; ++k) s += cat[k] * W1[k*CH_HID + tid];
        hid[tid] = fmaxf(s, 0.f);
    }
    __syncthreads();
    if (tid < 128) {
        float s = 0.f;
        for (int k = 0; k < CH_HID; ++k) s += hid[k] * W2[k*128 + tid];
        s = fmaxf(s, 0.f);
        att[b*256 + net*128 + tid] = 1.f / (1.f + expf(-s));
    }
}

// ---- main fused kernel: gate -> [64,256]bf16 tile -> MFMA MLP -> out ----
__global__ __launch_bounds__(256, 2)
void k_main(const float* __restrict__ lidar, const float* __restrict__ camT,
            const int* __restrict__ bidx, const int* __restrict__ yidx,
            const int* __restrict__ xidx, const float* __restrict__ att,
            const unsigned short* __restrict__ W1T, const unsigned short* __restrict__ W2T,
            float* __restrict__ out, int N) {
    __shared__ __align__(16) unsigned short sA[64][264];   // +8 pad
    __shared__ __align__(16) unsigned short sB[256][72];
    __shared__ float satt[NB*256];
    __shared__ int srow[64];
    __shared__ int sbb[64];
    const int tid = threadIdx.x;
    const int v0 = blockIdx.x * 64;

    // stage att + per-voxel row/batch
    for (int i = 0; i < 4; ++i) satt[i*256 + tid] = att[i*256 + tid];
    if (tid < 64) {
        int v = v0 + tid;
        int b = 0, row = 0;
        if (v < N) {
            b = bidx[v];
            row = min(b*SPATIAL + yidx[v]*WWW + xidx[v], SPATIAL - 2);
        }
        sbb[tid] = b;
        srow[tid] = row;
    }
    __syncthreads();

    // prologue: fused[m][c] = gated features, bf16, into sA.
    // 16 independent float4 iterations; wave j covers voxel (j*4+wave)'s 256 ch
    {
        const int c = (tid & 63) * 4;
        const bool cam = (c >= 128);
        for (int j = 0; j < 16; ++j) {
            int m = j*4 + (tid >> 6);
            int v = v0 + m;
            v4f val = {0.f, 0.f, 0.f, 0.f};
            if (v < N) {
                int b = sbb[m];
                const float* src = cam ? &camT[srow[m]*128 + (c - 128)]
                                       : &lidar[(size_t)v*128 + c];
                v4f x = *(const v4f*)src;
                for (int jj = 0; jj < 4; ++jj)
                    val[jj] = x[jj] * satt[b*256 + c + jj];
            }
            v4s pk;
            for (int jj = 0; jj < 4; ++jj) pk[jj] = (short)f2bf(val[jj]);
            *(v4s*)&sA[m][c] = pk;
        }
    }

    const int wave = tid >> 6;
    const int lane = tid & 63;
    const int ml = lane & 15;       // A: m row / B: n col
    const int q = lane >> 4;        // quad: k = q*8 + j

    for (int layer = 0; layer < 2; ++layer) {
        const unsigned short* WT = layer ? W2T : W1T;
        v4f acc[4][4];
        const v4f zz = {0.f, 0.f, 0.f, 0.f};
        for (int rt = 0; rt < 4; ++rt)
            for (int ct = 0; ct < 4; ++ct) acc[rt][ct] = zz;

        for (int k0 = 0; k0 < 256; k0 += 64) {
            __syncthreads();   // prev chunk / prologue / h-writes done
            for (int i = 0; i < 8; ++i) {
                int id = i*256 + tid;
                int n = id >> 3;
                int seg = (id & 7) * 8;
                *(v8s*)&sB[n][seg] = *(const v8s*)&WT[n*256 + k0 + seg];
            }
            __syncthreads();
            for (int ks = 0; ks < 2; ++ks) {
                v8s a[4];
                const int ka = k0 + ks*32 + q*8;
                for (int rt = 0; rt < 4; ++rt)
                    a[rt] = *(const v8s*)&sA[rt*16 + ml][ka];
                const int kb = ks*32 + q*8;
                for (int ct = 0; ct < 4; ++ct) {
                    v8s bf = *(const v8s*)&sB[wave*64 + ct*16 + ml][kb];
                    for (int rt = 0; rt < 4; ++rt)
                        acc[rt][ct] = __builtin_amdgcn_mfma_f32_16x16x32_bf16(
                            a[rt], bf, acc[rt][ct], 0, 0, 0);
                }
            }
        }
        __syncthreads();   // all sA reads done before overwrite / stores
        if (layer == 0) {
            // C/D layout: col = lane&15, row = q*4 + reg
            for (int rt = 0; rt < 4; ++rt)
                for (int ct = 0; ct < 4; ++ct)
                    for (int r = 0; r < 4; ++r)
                        sA[rt*16 + q*4 + r][wave*64 + ct*16 + ml] =
                            f2bf(fmaxf(acc[rt][ct][r], 0.f));
        } else {
            for (int rt = 0; rt < 4; ++rt)
                for (int ct = 0; ct < 4; ++ct) {
                    const int col = wave*64 + ct*16 + ml;
                    for (int r = 0; r < 4; ++r) {
                        int v = v0 + rt*16 + q*4 + r;
                        if (v < N) out[(size_t)v*256 + col] = fmaxf(acc[rt][ct][r], 0.f);
                    }
                }
        }
    }
}

extern "C" void kernel_launch(void* const* d_in, const int* in_sizes, int n_in,
                              void* d_out, int out_size, void* d_ws, size_t ws_size,
                              hipStream_t stream) {
    const float* lidar = (const float*)d_in[0];
    const float* img   = (const float*)d_in[1];
    const int*   bidx  = (const int*)d_in[2];
    const int*   yidx  = (const int*)d_in[3];
    const int*   xidx  = (const int*)d_in[4];
    const float* Wl1   = (const float*)d_in[5];
    const float* Wl2   = (const float*)d_in[6];
    const float* Wc1   = (const float*)d_in[7];
    const float* Wc2   = (const float*)d_in[8];
    const float* Wf1   = (const float*)d_in[9];
    const float* Wf2   = (const float*)d_in[10];
    float* out = (float*)d_out;
    const int N = in_sizes[0] / 128;

    // ws layout: [stats 8KB][att 4KB][pad to 16KB][W1T 128KB][W2T 128KB][camT 16.6MB]
    unsigned* stats = (unsigned*)d_ws;
    float* att = (float*)((char*)d_ws + 8192);
    unsigned short* W1T = (unsigned short*)((char*)d_ws + 16384);
    unsigned short* W2T = (unsigned short*)((char*)d_ws + 16384 + 131072);
    float* camT = (float*)((char*)d_ws + 16384 + 262144);

    k_init<<<8, 256, 0, stream>>>(stats);
    k_prep<<<dim3(64, 2), 256, 0, stream>>>(Wf1, Wf2, W1T, W2T);
    k_timg<<<dim3((SPATIAL + 31) / 32, 4), 256, 0, stream>>>(img, camT);
    const int rblocks = 640;
    const int chunk = (N + rblocks - 1) / rblocks;   // 250 <= 256
    k_reduce<<<rblocks, 256, 0, stream>>>(lidar, camT, bidx, yidx, xidx, stats, N, chunk);
    k_mlp<<<8, 256, 0, stream>>>(stats, Wl1, Wl2, Wc1, Wc2, att);
    k_main<<<(N + 63) / 64, 256, 0, stream>>>(lidar, camT, bidx, yidx, xidx, att, W1T, W2T, out, N);
}

// Round 3
// 467.539 us; speedup vs baseline: 1.3702x; 1.0561x over previous
//
#include <hip/hip_runtime.h>
#include <math.h>

#define NB 4
#define HH 180
#define WWW 180
#define SPATIAL (HH*WWW)     // 32400
#define CH_HID 170
#define CLAMP_ROW (SPATIAL-2)

typedef short v8s __attribute__((ext_vector_type(8)));
typedef short v4s __attribute__((ext_vector_type(4)));
typedef float v4f __attribute__((ext_vector_type(4)));

__device__ __forceinline__ unsigned fmap(float f) {
    unsigned u = __float_as_uint(f);
    return (u & 0x80000000u) ? ~u : (u | 0x80000000u);
}
__device__ __forceinline__ float funmap(unsigned u) {
    unsigned b = (u & 0x80000000u) ? (u & 0x7FFFFFFFu) : ~u;
    return __uint_as_float(b);
}
__device__ __forceinline__ unsigned short f2bf(float f) {
    unsigned u = __float_as_uint(f);
    u += 0x7FFFu + ((u >> 16) & 1);
    return (unsigned short)(u >> 16);
}

// ---- transpose Wf1/Wf2 [k][n] fp32 -> WT [n][k] bf16 ----
__global__ void k_prep(const float* __restrict__ Wf1, const float* __restrict__ Wf2,
                       unsigned short* __restrict__ W1T, unsigned short* __restrict__ W2T) {
    const float* W = blockIdx.y ? Wf2 : Wf1;
    unsigned short* WT = blockIdx.y ? W2T : W1T;
    __shared__ float t[32][33];
    int bx = blockIdx.x & 7, by = blockIdx.x >> 3;
    int lx = threadIdx.x & 31, ly = threadIdx.x >> 5;
    for (int i = 0; i < 4; ++i)
        t[ly + i*8][lx] = W[(by*32 + ly + i*8)*256 + bx*32 + lx];
    __syncthreads();
    for (int i = 0; i < 4; ++i)
        WT[(bx*32 + ly + i*8)*256 + by*32 + lx] = f2bf(t[lx][ly + i*8]);
}

// ---- setup: stats init (first 8 blocks of row 0) + transpose img batch 0 ----
__global__ void k_setup(const float* __restrict__ img, float* __restrict__ camT,
                        unsigned* __restrict__ stats) {
    if (blockIdx.y == 0 && blockIdx.x < 8) {
        int i = blockIdx.x * 256 + threadIdx.x;
        int j = i & 511;
        bool is_min = (j < 128) || (j >= 256 && j < 384);
        stats[i] = is_min ? 0xFFFFFFFFu : 0u;
    }
    __shared__ float tile[32][33];
    int s0 = blockIdx.x * 32, c0 = blockIdx.y * 32;
    int lx = threadIdx.x & 31, ly = threadIdx.x >> 5;
    for (int i = 0; i < 4; ++i) {
        int s = s0 + lx;
        if (s < SPATIAL)
            tile[ly + i*8][lx] = img[(c0 + ly + i*8) * SPATIAL + s];
    }
    __syncthreads();
    for (int i = 0; i < 4; ++i) {
        int s = s0 + ly + i*8;
        if (s < SPATIAL)
            camT[s*128 + c0 + lx] = tile[lx][ly + i*8];
    }
}

// ---- segment min/max; batch boundaries block-uniform; branch-free inner loop ----
__global__ __launch_bounds__(256)
void k_reduce(const float* __restrict__ lidar, const float* __restrict__ camT,
              const int* __restrict__ bidx, const int* __restrict__ yidx,
              const int* __restrict__ xidx,
              unsigned* __restrict__ stats, int N, int chunk) {
    __shared__ int sb[256];
    __shared__ int srow[256];
    __shared__ v4f redmn[4][64];
    __shared__ v4f redmx[4][64];
    const int tid = threadIdx.x;
    const int vbeg = blockIdx.x * chunk;
    const int cnt = min(chunk, N - vbeg);
    if (cnt <= 0) return;
    if (tid < cnt) {
        int v = vbeg + tid;
        sb[tid] = bidx[v];
        srow[tid] = min(yidx[v]*WWW + xidx[v] + sb[tid]*SPATIAL, CLAMP_ROW);
    }
    __syncthreads();

    const int sub = tid >> 6;              // voxel slot 0..3 (wave-uniform)
    const int lane = tid & 63;
    const int c4 = lane * 4;               // 0..252
    const bool cam = (c4 >= 128);
    const int cc = cam ? (c4 - 128) : c4;
    const int min_off = cam ? (c4 + 128) : c4;

    const int b_first = sb[0], b_last = sb[cnt - 1];
    int s0 = 0;
    for (int bb = b_first; bb <= b_last; ++bb) {
        int s1 = cnt;
        if (bb < b_last) {                 // uniform binary search: first idx with sb>bb
            int lo = s0, hi = cnt;
            while (lo < hi) { int mid = (lo + hi) >> 1; if (sb[mid] > bb) hi = mid; else lo = mid + 1; }
            s1 = lo;
        }
        float mn0 = INFINITY, mn1 = INFINITY, mn2 = INFINITY, mn3 = INFINITY;
        float mx0 = -INFINITY, mx1 = -INFINITY, mx2 = -INFINITY, mx3 = -INFINITY;
        const bool skipload = cam && (bb > 0);   // clamp bug: all rows -> CLAMP_ROW
        if (!skipload) {
            #pragma unroll 4
            for (int idx = s0 + sub; idx < s1; idx += 4) {
                const float* src = cam ? &camT[(size_t)srow[idx]*128 + cc]
                                       : &lidar[(size_t)(vbeg + idx)*128 + c4];
                v4f val = *(const v4f*)src;
                mn0 = fminf(mn0, val[0]); mx0 = fmaxf(mx0, val[0]);
                mn1 = fminf(mn1, val[1]); mx1 = fmaxf(mx1, val[1]);
                mn2 = fminf(mn2, val[2]); mx2 = fmaxf(mx2, val[2]);
                mn3 = fminf(mn3, val[3]); mx3 = fmaxf(mx3, val[3]);
            }
        } else {
            v4f cv = *(const v4f*)&camT[(size_t)CLAMP_ROW*128 + cc];
            mn0 = mx0 = cv[0]; mn1 = mx1 = cv[1]; mn2 = mx2 = cv[2]; mn3 = mx3 = cv[3];
        }
        redmn[sub][lane] = (v4f){mn0, mn1, mn2, mn3};
        redmx[sub][lane] = (v4f){mx0, mx1, mx2, mx3};
        __syncthreads();
        if (sub == 0) {
            v4f a0 = redmn[0][lane], a1 = redmn[1][lane], a2 = redmn[2][lane], a3 = redmn[3][lane];
            v4f b0 = redmx[0][lane], b1 = redmx[1][lane], b2 = redmx[2][lane], b3 = redmx[3][lane];
            int base = bb*512 + min_off;
            for (int j = 0; j < 4; ++j) {
                float mn = fminf(fminf(a0[j], a1[j]), fminf(a2[j], a3[j]));
                float mx = fmaxf(fmaxf(b0[j], b1[j]), fmaxf(b2[j], b3[j]));
                atomicMin(&stats[base + j], fmap(mn));
                atomicMax(&stats[base + 128 + j], fmap(mx));
            }
        }
        __syncthreads();
        s0 = s1;
    }
}

// ---- tiny attention MLPs: block = (batch, net) ----
__global__ void k_mlp(const unsigned* __restrict__ stats,
                      const float* __restrict__ Wl1, const float* __restrict__ Wl2,
                      const float* __restrict__ Wc1, const float* __restrict__ Wc2,
                      float* __restrict__ att) {
    __shared__ float cat[512];
    __shared__ float hid[CH_HID];
    int b = blockIdx.x >> 1;
    int net = blockIdx.x & 1;
    const float* W1 = net ? Wc1 : Wl1;
    const float* W2 = net ? Wc2 : Wl2;
    int tid = threadIdx.x;
    for (int j = tid; j < 512; j += 256) cat[j] = funmap(stats[b*512 + j]);
    __syncthreads();
    if (tid < CH_HID) {
        float s = 0.f;
        for (int k = 0; k < 512; ++k) s += cat[k] * W1[k*CH_HID + tid];
        hid[tid] = fmaxf(s, 0.f);
    }
    __syncthreads();
    if (tid < 128) {
        float s = 0.f;
        for (int k = 0; k < CH_HID; ++k) s += hid[k] * W2[k*128 + tid];
        s = fmaxf(s, 0.f);
        att[b*256 + net*128 + tid] = 1.f / (1.f + expf(-s));
    }
}

// ---- main fused kernel: gate -> [64,256]bf16 tile -> MFMA MLP (B direct from L2) ----
__global__ __launch_bounds__(256, 3)
void k_main(const float* __restrict__ lidar, const float* __restrict__ camT,
            const int* __restrict__ bidx, const int* __restrict__ yidx,
            const int* __restrict__ xidx, const float* __restrict__ att,
            const unsigned short* __restrict__ W1T, const unsigned short* __restrict__ W2T,
            float* __restrict__ out, int N) {
    __shared__ __align__(16) unsigned short sA[64][264];   // 33.8 KB, +8 pad
    __shared__ float satt[NB*256];
    __shared__ int srow[64];
    __shared__ int sbb[64];
    const int tid = threadIdx.x;
    const int v0 = blockIdx.x * 64;

    for (int i = 0; i < 4; ++i) satt[i*256 + tid] = att[i*256 + tid];
    if (tid < 64) {
        int v = v0 + tid;
        int b = 0, row = 0;
        if (v < N) {
            b = bidx[v];
            row = min(b*SPATIAL + yidx[v]*WWW + xidx[v], CLAMP_ROW);
        }
        sbb[tid] = b;
        srow[tid] = row;
    }
    __syncthreads();

    { // prologue: gated features -> sA (bf16); wave-parallel float4 loads
        const int c = (tid & 63) * 4;
        const bool cam = (c >= 128);
        for (int j = 0; j < 16; ++j) {
            int m = j*4 + (tid >> 6);
            int v = v0 + m;
            v4f val = {0.f, 0.f, 0.f, 0.f};
            if (v < N) {
                int b = sbb[m];
                const float* src = cam ? &camT[(size_t)srow[m]*128 + (c - 128)]
                                       : &lidar[(size_t)v*128 + c];
                v4f x = *(const v4f*)src;
                for (int jj = 0; jj < 4; ++jj)
                    val[jj] = x[jj] * satt[b*256 + c + jj];
            }
            v4s pk;
            for (int jj = 0; jj < 4; ++jj) pk[jj] = (short)f2bf(val[jj]);
            *(v4s*)&sA[m][c] = pk;
        }
    }

    const int wave = tid >> 6;
    const int lane = tid & 63;
    const int ml = lane & 15;
    const int q = lane >> 4;

    for (int layer = 0; layer < 2; ++layer) {
        const unsigned short* WT = layer ? W2T : W1T;
        v4f acc[4][4];
        const v4f zz = {0.f, 0.f, 0.f, 0.f};
        for (int rt = 0; rt < 4; ++rt)
            for (int ct = 0; ct < 4; ++ct) acc[rt][ct] = zz;

        __syncthreads();   // sA ready (prologue / layer-0 writeback)
        // B-fragments direct from global (L2-hot, 64B-aligned contiguous runs)
        const unsigned short* wb = WT + (size_t)(wave*64 + ml)*256 + q*8;
        #pragma unroll
        for (int ks = 0; ks < 8; ++ks) {
            v8s a[4];
            const int ka = ks*32 + q*8;
            for (int rt = 0; rt < 4; ++rt)
                a[rt] = *(const v8s*)&sA[rt*16 + ml][ka];
            for (int ct = 0; ct < 4; ++ct) {
                v8s bfr = *(const v8s*)&wb[ct*16*256 + ks*32];
                for (int rt = 0; rt < 4; ++rt)
                    acc[rt][ct] = __builtin_amdgcn_mfma_f32_16x16x32_bf16(
                        a[rt], bfr, acc[rt][ct], 0, 0, 0);
            }
        }
        __syncthreads();   // all sA reads done before overwrite / stores
        if (layer == 0) {
            // C/D layout: col = lane&15, row = q*4 + reg
            for (int rt = 0; rt < 4; ++rt)
                for (int ct = 0; ct < 4; ++ct)
                    for (int r = 0; r < 4; ++r)
                        sA[rt*16 + q*4 + r][wave*64 + ct*16 + ml] =
                            f2bf(fmaxf(acc[rt][ct][r], 0.f));
        } else {
            for (int rt = 0; rt < 4; ++rt)
                for (int ct = 0; ct < 4; ++ct) {
                    const int col = wave*64 + ct*16 + ml;
                    for (int r = 0; r < 4; ++r) {
                        int v = v0 + rt*16 + q*4 + r;
                        if (v < N) out[(size_t)v*256 + col] = fmaxf(acc[rt][ct][r], 0.f);
                    }
                }
        }
    }
}

extern "C" void kernel_launch(void* const* d_in, const int* in_sizes, int n_in,
                              void* d_out, int out_size, void* d_ws, size_t ws_size,
                              hipStream_t stream) {
    const float* lidar = (const float*)d_in[0];
    const float* img   = (const float*)d_in[1];
    const int*   bidx  = (const int*)d_in[2];
    const int*   yidx  = (const int*)d_in[3];
    const int*   xidx  = (const int*)d_in[4];
    const float* Wl1   = (const float*)d_in[5];
    const float* Wl2   = (const float*)d_in[6];
    const float* Wc1   = (const float*)d_in[7];
    const float* Wc2   = (const float*)d_in[8];
    const float* Wf1   = (const float*)d_in[9];
    const float* Wf2   = (const float*)d_in[10];
    float* out = (float*)d_out;
    const int N = in_sizes[0] / 128;

    // ws: [stats 8KB][att 4KB][pad to 16KB][W1T 128KB][W2T 128KB][camT 16.6MB]
    unsigned* stats = (unsigned*)d_ws;
    float* att = (float*)((char*)d_ws + 8192);
    unsigned short* W1T = (unsigned short*)((char*)d_ws + 16384);
    unsigned short* W2T = (unsigned short*)((char*)d_ws + 16384 + 131072);
    float* camT = (float*)((char*)d_ws + 16384 + 262144);

    k_prep<<<dim3(64, 2), 256, 0, stream>>>(Wf1, Wf2, W1T, W2T);
    k_setup<<<dim3((SPATIAL + 31) / 32, 4), 256, 0, stream>>>(img, camT, stats);
    const int rblocks = 1280;
    const int chunk = (N + rblocks - 1) / rblocks;   // 125 <= 256
    k_reduce<<<rblocks, 256, 0, stream>>>(lidar, camT, bidx, yidx, xidx, stats, N, chunk);
    k_mlp<<<8, 256, 0, stream>>>(stats, Wl1, Wl2, Wc1, Wc2, att);
    k_main<<<(N + 63) / 64, 256, 0, stream>>>(lidar, camT, bidx, yidx, xidx, att, W1T, W2T, out, N);
}

// Round 4
// 443.370 us; speedup vs baseline: 1.4449x; 1.0545x over previous
//
#include <hip/hip_runtime.h>
#include <math.h>

#define NB 4
#define HH 180
#define WWW 180
#define SPATIAL (HH*WWW)     // 32400
#define CH_HID 170
#define CLAMP_ROW (SPATIAL-2)

typedef short v8s __attribute__((ext_vector_type(8)));
typedef short v4s __attribute__((ext_vector_type(4)));
typedef float v4f __attribute__((ext_vector_type(4)));

__device__ __forceinline__ unsigned fmap(float f) {
    unsigned u = __float_as_uint(f);
    return (u & 0x80000000u) ? ~u : (u | 0x80000000u);
}
__device__ __forceinline__ float funmap(unsigned u) {
    unsigned b = (u & 0x80000000u) ? (u & 0x7FFFFFFFu) : ~u;
    return __uint_as_float(b);
}
__device__ __forceinline__ unsigned short f2bf(float f) {
    unsigned u = __float_as_uint(f);
    u += 0x7FFFu + ((u >> 16) & 1);
    return (unsigned short)(u >> 16);
}

// ---- prep: swizzle Wf1/Wf2 [k][n] fp32 -> MFMA-fragment-ordered bf16 + stats init ----
// WS[(((nt*8)+ks)*64 + lane)*8 + j] = bf16(W[(ks*32 + q*8 + j)*256 + nt*16 + ml])
// so a wave's B-fragment load for (n-tile nt, k-chunk ks) is one contiguous 1KB burst.
__global__ void k_prep(const float* __restrict__ Wf1, const float* __restrict__ Wf2,
                       unsigned short* __restrict__ W1S, unsigned short* __restrict__ W2S,
                       unsigned* __restrict__ stats) {
    if (blockIdx.y == 0 && blockIdx.x < 8) {
        int i = blockIdx.x * 256 + threadIdx.x;
        int j = i & 511;
        bool is_min = (j < 128) || (j >= 256 && j < 384);
        stats[i] = is_min ? 0xFFFFFFFFu : 0u;
    }
    const float* W = blockIdx.y ? Wf2 : Wf1;
    unsigned short* WS = blockIdx.y ? W2S : W1S;
    const int tid = threadIdx.x;
    const int frag = blockIdx.x * 4 + (tid >> 6);   // 0..127 = nt*8+ks
    const int lane = tid & 63;
    const int nt = frag >> 3, ks = frag & 7;
    const int q = lane >> 4, ml = lane & 15;
    v8s pk;
    #pragma unroll
    for (int j = 0; j < 8; ++j)
        pk[j] = (short)f2bf(W[(ks*32 + q*8 + j)*256 + nt*16 + ml]);
    *(v8s*)&WS[(frag*64 + lane)*8] = pk;
}

// ---- setup: transpose img batch 0 [128][32400] -> camT [32400][128] fp32 ----
__global__ void k_setup(const float* __restrict__ img, float* __restrict__ camT) {
    __shared__ float tile[32][33];
    int s0 = blockIdx.x * 32, c0 = blockIdx.y * 32;
    int lx = threadIdx.x & 31, ly = threadIdx.x >> 5;
    for (int i = 0; i < 4; ++i) {
        int s = s0 + lx;
        if (s < SPATIAL)
            tile[ly + i*8][lx] = img[(c0 + ly + i*8) * SPATIAL + s];
    }
    __syncthreads();
    for (int i = 0; i < 4; ++i) {
        int s = s0 + ly + i*8;
        if (s < SPATIAL)
            camT[s*128 + c0 + lx] = tile[lx][ly + i*8];
    }
}

// ---- segment min/max; batch boundaries block-uniform; branch-free inner loop ----
__global__ __launch_bounds__(256)
void k_reduce(const float* __restrict__ lidar, const float* __restrict__ camT,
              const int* __restrict__ bidx, const int* __restrict__ yidx,
              const int* __restrict__ xidx,
              unsigned* __restrict__ stats, int N, int chunk) {
    __shared__ int sb[256];
    __shared__ int srow[256];
    __shared__ v4f redmn[4][64];
    __shared__ v4f redmx[4][64];
    const int tid = threadIdx.x;
    const int vbeg = blockIdx.x * chunk;
    const int cnt = min(chunk, N - vbeg);
    if (cnt <= 0) return;
    if (tid < cnt) {
        int v = vbeg + tid;
        sb[tid] = bidx[v];
        srow[tid] = min(yidx[v]*WWW + xidx[v] + sb[tid]*SPATIAL, CLAMP_ROW);
    }
    __syncthreads();

    const int sub = tid >> 6;
    const int lane = tid & 63;
    const int c4 = lane * 4;
    const bool cam = (c4 >= 128);
    const int cc = cam ? (c4 - 128) : c4;
    const int min_off = cam ? (c4 + 128) : c4;

    const int b_first = sb[0], b_last = sb[cnt - 1];
    int s0 = 0;
    for (int bb = b_first; bb <= b_last; ++bb) {
        int s1 = cnt;
        if (bb < b_last) {
            int lo = s0, hi = cnt;
            while (lo < hi) { int mid = (lo + hi) >> 1; if (sb[mid] > bb) hi = mid; else lo = mid + 1; }
            s1 = lo;
        }
        float mn0 = INFINITY, mn1 = INFINITY, mn2 = INFINITY, mn3 = INFINITY;
        float mx0 = -INFINITY, mx1 = -INFINITY, mx2 = -INFINITY, mx3 = -INFINITY;
        const bool skipload = cam && (bb > 0);   // clamp bug: all cam rows -> CLAMP_ROW
        if (!skipload) {
            #pragma unroll 4
            for (int idx = s0 + sub; idx < s1; idx += 4) {
                const float* src = cam ? &camT[(size_t)srow[idx]*128 + cc]
                                       : &lidar[(size_t)(vbeg + idx)*128 + c4];
                v4f val = *(const v4f*)src;
                mn0 = fminf(mn0, val[0]); mx0 = fmaxf(mx0, val[0]);
                mn1 = fminf(mn1, val[1]); mx1 = fmaxf(mx1, val[1]);
                mn2 = fminf(mn2, val[2]); mx2 = fmaxf(mx2, val[2]);
                mn3 = fminf(mn3, val[3]); mx3 = fmaxf(mx3, val[3]);
            }
        } else {
            v4f cv = *(const v4f*)&camT[(size_t)CLAMP_ROW*128 + cc];
            mn0 = mx0 = cv[0]; mn1 = mx1 = cv[1]; mn2 = mx2 = cv[2]; mn3 = mx3 = cv[3];
        }
        redmn[sub][lane] = (v4f){mn0, mn1, mn2, mn3};
        redmx[sub][lane] = (v4f){mx0, mx1, mx2, mx3};
        __syncthreads();
        if (sub == 0) {
            v4f a0 = redmn[0][lane], a1 = redmn[1][lane], a2 = redmn[2][lane], a3 = redmn[3][lane];
            v4f b0 = redmx[0][lane], b1 = redmx[1][lane], b2 = redmx[2][lane], b3 = redmx[3][lane];
            int base = bb*512 + min_off;
            for (int j = 0; j < 4; ++j) {
                float mn = fminf(fminf(a0[j], a1[j]), fminf(a2[j], a3[j]));
                float mx = fmaxf(fmaxf(b0[j], b1[j]), fmaxf(b2[j], b3[j]));
                atomicMin(&stats[base + j], fmap(mn));
                atomicMax(&stats[base + 128 + j], fmap(mx));
            }
        }
        __syncthreads();
        s0 = s1;
    }
}

// ---- tiny attention MLPs: block = (batch, net) ----
__global__ void k_mlp(const unsigned* __restrict__ stats,
                      const float* __restrict__ Wl1, const float* __restrict__ Wl2,
                      const float* __restrict__ Wc1, const float* __restrict__ Wc2,
                      float* __restrict__ att) {
    __shared__ float cat[512];
    __shared__ float hid[CH_HID];
    int b = blockIdx.x >> 1;
    int net = blockIdx.x & 1;
    const float* W1 = net ? Wc1 : Wl1;
    const float* W2 = net ? Wc2 : Wl2;
    int tid = threadIdx.x;
    for (int j = tid; j < 512; j += 256) cat[j] = funmap(stats[b*512 + j]);
    __syncthreads();
    if (tid < CH_HID) {
        float s = 0.f;
        #pragma unroll 16
        for (int k = 0; k < 512; ++k) s += cat[k] * W1[k*CH_HID + tid];
        hid[tid] = fmaxf(s, 0.f);
    }
    __syncthreads();
    if (tid < 128) {
        float s = 0.f;
        #pragma unroll 10
        for (int k = 0; k < CH_HID; ++k) s += hid[k] * W2[k*128 + tid];
        s = fmaxf(s, 0.f);
        att[b*256 + net*128 + tid] = 1.f / (1.f + expf(-s));
    }
}

// ---- main fused kernel: gate -> [64,256]bf16 tile -> MFMA MLP, swizzled-B, vec stores ----
__global__ __launch_bounds__(256, 3)
void k_main(const float* __restrict__ lidar, const float* __restrict__ camT,
            const int* __restrict__ bidx, const int* __restrict__ yidx,
            const int* __restrict__ xidx, const float* __restrict__ att,
            const unsigned short* __restrict__ W1S, const unsigned short* __restrict__ W2S,
            float* __restrict__ out, int N) {
    __shared__ __align__(16) char smem[64 * 264 * 2];          // 33.8 KB, dual-use
    unsigned short (*sA)[264] = (unsigned short(*)[264])smem;  // bf16 A tile, +8 pad
    float* sAf = (float*)smem;                                  // fp32 out staging, stride 260
    __shared__ int srow[64];
    __shared__ int sbb[64];
    const int tid = threadIdx.x;
    const int v0 = blockIdx.x * 64;

    if (tid < 64) {
        int v = v0 + tid;
        int b = 0, row = 0;
        if (v < N) {
            b = bidx[v];
            row = min(b*SPATIAL + yidx[v]*WWW + xidx[v], CLAMP_ROW);
        }
        sbb[tid] = b;
        srow[tid] = row;
    }
    const int c = (tid & 63) * 4;
    const bool cam = (c >= 128);
    v4f attv0 = *(const v4f*)&att[0*256 + c];
    v4f attv1 = *(const v4f*)&att[1*256 + c];
    v4f attv2 = *(const v4f*)&att[2*256 + c];
    v4f attv3 = *(const v4f*)&att[3*256 + c];
    __syncthreads();

    // prologue: 2 rounds of 8 prefetched float4 loads -> gate -> bf16 -> sA
    #pragma unroll
    for (int half = 0; half < 2; ++half) {
        v4f x[8]; int bm[8];
        #pragma unroll
        for (int j = 0; j < 8; ++j) {
            int m = (half*8 + j)*4 + (tid >> 6);
            int vc = min(v0 + m, N - 1);
            bm[j] = sbb[m];
            const float* src = cam ? &camT[(size_t)srow[m]*128 + (c - 128)]
                                   : &lidar[(size_t)vc*128 + c];
            x[j] = *(const v4f*)src;
        }
        #pragma unroll
        for (int j = 0; j < 8; ++j) {
            int m = (half*8 + j)*4 + (tid >> 6);
            int b = bm[j];
            v4f a = attv0;
            if (b == 1) a = attv1;
            if (b == 2) a = attv2;
            if (b == 3) a = attv3;
            v4f val = x[j] * a;
            v4s pk;
            #pragma unroll
            for (int jj = 0; jj < 4; ++jj) pk[jj] = (short)f2bf(val[jj]);
            *(v4s*)&sA[m][c] = pk;
        }
    }

    const int wave = tid >> 6;
    const int lane = tid & 63;
    const int ml = lane & 15;
    const int q = lane >> 4;

    v4f acc[4][4];
    for (int layer = 0; layer < 2; ++layer) {
        const unsigned short* WS = layer ? W2S : W1S;
        const v4f zz = {0.f, 0.f, 0.f, 0.f};
        for (int rt = 0; rt < 4; ++rt)
            for (int ct = 0; ct < 4; ++ct) acc[rt][ct] = zz;

        __syncthreads();   // sA ready
        #pragma unroll
        for (int ks = 0; ks < 8; ++ks) {
            v8s a[4];
            const int ka = ks*32 + q*8;
            #pragma unroll
            for (int rt = 0; rt < 4; ++rt)
                a[rt] = *(const v8s*)&sA[rt*16 + ml][ka];
            #pragma unroll
            for (int ct = 0; ct < 4; ++ct) {
                // swizzled layout: one contiguous 1KB burst per wave
                v8s bfr = *(const v8s*)&WS[(((wave*4 + ct)*8 + ks)*64 + lane)*8];
                #pragma unroll
                for (int rt = 0; rt < 4; ++rt)
                    acc[rt][ct] = __builtin_amdgcn_mfma_f32_16x16x32_bf16(
                        a[rt], bfr, acc[rt][ct], 0, 0, 0);
            }
        }
        __syncthreads();   // all sA reads done
        if (layer == 0) {
            // C/D layout: col = lane&15, row = q*4 + reg
            for (int rt = 0; rt < 4; ++rt)
                for (int ct = 0; ct < 4; ++ct)
                    for (int r = 0; r < 4; ++r)
                        sA[rt*16 + q*4 + r][wave*64 + ct*16 + ml] =
                            f2bf(fmaxf(acc[rt][ct][r], 0.f));
        }
    }

    // epilogue: two 32-row passes through LDS (fp32, stride 260: 2-way banks = free),
    // then fully-coalesced float4 stores
    const int c4 = (tid & 63) * 4;
    #pragma unroll
    for (int p = 0; p < 2; ++p) {
        __syncthreads();
        #pragma unroll
        for (int rt = 2*p; rt < 2*p + 2; ++rt)
            for (int ct = 0; ct < 4; ++ct)
                for (int r = 0; r < 4; ++r)
                    sAf[((rt - 2*p)*16 + q*4 + r)*260 + wave*64 + ct*16 + ml] =
                        fmaxf(acc[rt][ct][r], 0.f);
        __syncthreads();
        #pragma unroll
        for (int i = 0; i < 8; ++i) {
            int rl = (tid >> 6) + i*4;      // 0..31
            int v = v0 + p*32 + rl;
            if (v < N)
                *(v4f*)&out[(size_t)v*256 + c4] = *(const v4f*)&sAf[rl*260 + c4];
        }
    }
}

extern "C" void kernel_launch(void* const* d_in, const int* in_sizes, int n_in,
                              void* d_out, int out_size, void* d_ws, size_t ws_size,
                              hipStream_t stream) {
    const float* lidar = (const float*)d_in[0];
    const float* img   = (const float*)d_in[1];
    const int*   bidx  = (const int*)d_in[2];
    const int*   yidx  = (const int*)d_in[3];
    const int*   xidx  = (const int*)d_in[4];
    const float* Wl1   = (const float*)d_in[5];
    const float* Wl2   = (const float*)d_in[6];
    const float* Wc1   = (const float*)d_in[7];
    const float* Wc2   = (const float*)d_in[8];
    const float* Wf1   = (const float*)d_in[9];
    const float* Wf2   = (const float*)d_in[10];
    float* out = (float*)d_out;
    const int N = in_sizes[0] / 128;

    // ws: [stats 8KB][att 4KB][pad to 16KB][W1S 128KB][W2S 128KB][camT 16.6MB]
    unsigned* stats = (unsigned*)d_ws;
    float* att = (float*)((char*)d_ws + 8192);
    unsigned short* W1S = (unsigned short*)((char*)d_ws + 16384);
    unsigned short* W2S = (unsigned short*)((char*)d_ws + 16384 + 131072);
    float* camT = (float*)((char*)d_ws + 16384 + 262144);

    k_prep<<<dim3(32, 2), 256, 0, stream>>>(Wf1, Wf2, W1S, W2S, stats);
    k_setup<<<dim3((SPATIAL + 31) / 32, 4), 256, 0, stream>>>(img, camT);
    const int rblocks = 2560;
    const int chunk = (N + rblocks - 1) / rblocks;   // 63
    k_reduce<<<rblocks, 256, 0, stream>>>(lidar, camT, bidx, yidx, xidx, stats, N, chunk);
    k_mlp<<<8, 256, 0, stream>>>(stats, Wl1, Wl2, Wc1, Wc2, att);
    k_main<<<(N + 63) / 64, 256, 0, stream>>>(lidar, camT, bidx, yidx, xidx, att, W1S, W2S, out, N);
}